// Round 5
// baseline (310.042 us; speedup 1.0000x reference)
//
#include <hip/hip_runtime.h>
#include <math.h>

#define NUM_EMB 8192
#define DIM     4
#define NTOK    32768                 // B*L = 8*4096
#define NCHUNK  32
#define CHUNK   (NUM_EMB / NCHUNK)    // 256 embeddings per chunk
#define BATCH   8
#define NBATCH  (CHUNK / BATCH)       // 32 batches per chunk
#define TPB     256
#define TPT     2                     // tokens per thread
#define TOKBLK  (TPB * TPT)           // 512 tokens per block/range
#define NRANGE  (NTOK / TOKBLK)       // 64 token-ranges

// Constant address space: wave-uniform loads -> s_load (scalar pipe only).
#define CONSTANT __attribute__((address_space(4)))
typedef const float CONSTANT* cfloat_p;

// identical fmaf chain everywhere -> bitwise-equal dots (exact re-find)
__device__ __forceinline__ float dot4(const float4& a,
                                      float ex, float ey, float ez, float ew) {
    return fmaf(a.w, ew, fmaf(a.z, ez, fmaf(a.y, ey, a.x * ex)));
}

// Single fused kernel. grid = (NRANGE, NCHUNK) = 2048 blocks, 8 waves/SIMD.
// Phase 1 (all blocks): per (token,chunk) value-max over 8-embedding batches,
//   store (best, batch-id) partials.
// Phase 2 (per range, last-arriving chunk-block via ticket): merge 32 chunk
//   partials for 512 tokens, exact re-scan of winning batch, sum |x-e|.
// Phase 3 (last-arriving range via second ticket): sum 64 range sums -> out.
__global__ __launch_bounds__(TPB, 8) void vq_fused(
    const float4* __restrict__ x,
    const float*  __restrict__ emb,
    float* __restrict__ part_best,
    int*   __restrict__ part_batch,
    float* __restrict__ range_sum,
    unsigned* __restrict__ cnt,       // [NRANGE], memset 0 before launch
    unsigned* __restrict__ cnt2,      // [1],      memset 0 before launch
    float* __restrict__ out) {

    const int range = blockIdx.x;     // token-range 0..63
    const int chunk = blockIdx.y;     // chunk 0..31
    cfloat_p ef = (cfloat_p)(emb + (size_t)chunk * CHUNK * DIM);

    const int t0 = range * TOKBLK + threadIdx.x;   // coalesced
    const int t1 = t0 + TPB;                       // coalesced
    const float4 x0 = x[t0];
    const float4 x1 = x[t1];

    float best0 = -INFINITY, best1 = -INFINITY;
    int   bb0 = 0, bb1 = 0;
    int   nb  = 0;

    #pragma unroll 2
    for (int b = 0; b < NBATCH; ++b) {
        float d0[BATCH], d1[BATCH];
        #pragma unroll
        for (int j = 0; j < BATCH; ++j) {
            const float ex = ef[(b * BATCH + j) * 4 + 0];
            const float ey = ef[(b * BATCH + j) * 4 + 1];
            const float ez = ef[(b * BATCH + j) * 4 + 2];
            const float ew = ef[(b * BATCH + j) * 4 + 3];
            d0[j] = dot4(x0, ex, ey, ez, ew);
            d1[j] = dot4(x1, ex, ey, ez, ew);
        }
        float m0 = fmaxf(fmaxf(fmaxf(d0[0], d0[1]), fmaxf(d0[2], d0[3])),
                         fmaxf(fmaxf(d0[4], d0[5]), fmaxf(d0[6], d0[7])));
        float m1 = fmaxf(fmaxf(fmaxf(d1[0], d1[1]), fmaxf(d1[2], d1[3])),
                         fmaxf(fmaxf(d1[4], d1[5]), fmaxf(d1[6], d1[7])));
        bool c0 = m0 > best0;         // strict > : earliest batch wins ties
        bool c1 = m1 > best1;
        bb0   = c0 ? nb : bb0;
        bb1   = c1 ? nb : bb1;
        best0 = c0 ? m0 : best0;
        best1 = c1 ? m1 : best1;
        ++nb;
    }

    part_best [chunk * NTOK + t0] = best0;
    part_batch[chunk * NTOK + t0] = chunk * NBATCH + bb0;
    part_best [chunk * NTOK + t1] = best1;
    part_batch[chunk * NTOK + t1] = chunk * NBATCH + bb1;

    // ---- ticket: last chunk-block of this range merges the range ----
    __threadfence();
    __shared__ unsigned sOld;
    if (threadIdx.x == 0)
        sOld = __hip_atomic_fetch_add(&cnt[range], 1u, __ATOMIC_ACQ_REL,
                                      __HIP_MEMORY_SCOPE_AGENT);
    __syncthreads();
    if (sOld != NCHUNK - 1) return;

    // ---- phase 2: merge 512 tokens of this range (2 per thread) ----
    const volatile float* vbest  = (const volatile float*)part_best;
    const volatile int*   vbatch = (const volatile int*)part_batch;
    const float4* embv = (const float4*)emb;

    float s = 0.f;
    #pragma unroll
    for (int t = 0; t < TPT; ++t) {
        const int tok = range * TOKBLK + t * TPB + threadIdx.x;
        float best = -INFINITY;
        int   bb   = 0;
        #pragma unroll
        for (int c = 0; c < NCHUNK; ++c) {          // ascending c: first-max
            float v = vbest [c * NTOK + tok];
            int   i = vbatch[c * NTOK + tok];
            bool cc = v > best;
            best = cc ? v : best;
            bb   = cc ? i : bb;
        }
        const float4 xv = x[tok];
        // exact re-scan, ascending with found-guard -> lowest index wins
        float4 e = embv[bb * BATCH];
        bool found = false;
        #pragma unroll
        for (int j = 0; j < BATCH; ++j) {
            float4 c4 = embv[bb * BATCH + j];
            float dj = dot4(xv, c4.x, c4.y, c4.z, c4.w);
            bool hit = (dj == best) && !found;
            e = hit ? c4 : e;
            found = found || hit;
        }
        s += fabsf(xv.x - e.x) + fabsf(xv.y - e.y)
           + fabsf(xv.z - e.z) + fabsf(xv.w - e.w);
    }

    #pragma unroll
    for (int off = 32; off > 0; off >>= 1)
        s += __shfl_down(s, off, 64);

    __shared__ float ws[TPB / 64];
    __shared__ bool  sLast;
    if ((threadIdx.x & 63) == 0) ws[threadIdx.x >> 6] = s;
    __syncthreads();

    if (threadIdx.x == 0) {
        range_sum[range] = ws[0] + ws[1] + ws[2] + ws[3];
        __threadfence();
        unsigned old2 = __hip_atomic_fetch_add(cnt2, 1u, __ATOMIC_ACQ_REL,
                                               __HIP_MEMORY_SCOPE_AGENT);
        sLast = (old2 == NRANGE - 1);
    }
    __syncthreads();
    if (!sLast) return;

    // ---- phase 3: final 64-way sum (first wave only) ----
    if (threadIdx.x < 64) {
        float t = ((const volatile float*)range_sum)[threadIdx.x];
        #pragma unroll
        for (int off = 32; off > 0; off >>= 1)
            t += __shfl_down(t, off, 64);
        if (threadIdx.x == 0)
            out[0] = t * (2.0f / (float)(NTOK * DIM));
    }
}

extern "C" void kernel_launch(void* const* d_in, const int* in_sizes, int n_in,
                              void* d_out, int out_size, void* d_ws, size_t ws_size,
                              hipStream_t stream) {
    const float4* x4  = (const float4*)d_in[0];   // [8,4096,4] fp32
    const float*  emb = (const float*)d_in[1];    // [8192,4]   fp32
    float* out = (float*)d_out;

    // ws: part_best (4 MB) | part_batch (4 MB) | range_sum | cnt | cnt2
    char* w = (char*)d_ws;
    float*    part_best  = (float*)w;
    int*      part_batch = (int*)(w + (size_t)NCHUNK * NTOK * 4);
    float*    range_sum  = (float*)(w + (size_t)2 * NCHUNK * NTOK * 4);
    unsigned* cnt        = (unsigned*)(w + (size_t)2 * NCHUNK * NTOK * 4 + NRANGE * 4);
    unsigned* cnt2       = (unsigned*)(w + (size_t)2 * NCHUNK * NTOK * 4 + 2 * NRANGE * 4);

    // zero the tickets only (260 B); partials/range_sum are fully overwritten
    hipMemsetAsync(cnt, 0, (NRANGE + 1) * sizeof(unsigned), stream);

    dim3 g(NRANGE, NCHUNK);
    vq_fused<<<g, TPB, 0, stream>>>(x4, emb, part_best, part_batch,
                                    range_sum, cnt, cnt2, out);
}

// Round 6
// 171.383 us; speedup vs baseline: 1.8091x; 1.8091x over previous
//
#include <hip/hip_runtime.h>
#include <math.h>

#define NUM_EMB 8192
#define DIM     4
#define NTOK    32768                 // B*L = 8*4096
#define NCHUNK  16
#define CHUNK   (NUM_EMB / NCHUNK)    // 512 embeddings per chunk
#define BATCH   16
#define NBATCH  (CHUNK / BATCH)       // 32 batches per chunk
#define TPB     256
#define NMB     (NTOK / TPB)          // 128 merge blocks
#define IDBITS  9                     // NCHUNK*NBATCH = 512 batch ids
#define IDMASK  511u

typedef float v2f __attribute__((ext_vector_type(2)));

// Constant address space: wave-uniform loads -> s_load (scalar pipe).
// v2f loads keep (e.x,e.y)/(e.z,e.w) as aligned SGPR pairs -> natural
// VOP3P (v_pk_mul_f32 / v_pk_fma_f32) operands, no broadcast movs.
#define CONSTANT __attribute__((address_space(4)))
typedef const v2f CONSTANT* cv2p;

// Kernel A: per (token, chunk) value-max of dot(x,e) over 16-embedding
// batches; emit ONE uint32 key = sortable(best) top-23 bits | batch-id.
// grid = (128, 16) = 2048 blocks = 8 blocks/CU = 8 waves/SIMD (100% occ).
// Per pair: v_pk_mul + v_pk_fma + v_add + v_max = 4 issue slots.
__global__ __launch_bounds__(TPB, 8) void vq_scan(
    const float4* __restrict__ x,
    const float*  __restrict__ emb,
    unsigned* __restrict__ part,      // [NCHUNK][NTOK] packed keys
    unsigned* __restrict__ cnt) {

    const int chunk = blockIdx.y;
    cv2p ef = (cv2p)(emb + (size_t)chunk * CHUNK * DIM);

    const int tok = blockIdx.x * TPB + threadIdx.x;    // coalesced
    const float4 xv = x[tok];
    const v2f xy = {xv.x, xv.y};
    const v2f zw = {xv.z, xv.w};

    float best = -INFINITY;
    int   bb = 0, nb = 0;

    for (int b = 0; b < NBATCH; ++b) {
        float m;
        #pragma unroll
        for (int j = 0; j < BATCH; ++j) {
            v2f t = xy * ef[(b * BATCH + j) * 2];                          // v_pk_mul_f32
            t = __builtin_elementwise_fma(zw, ef[(b * BATCH + j) * 2 + 1], t); // v_pk_fma_f32
            float d = t.x + t.y;
            m = (j == 0) ? d : fmaxf(m, d);
        }
        bool c = m > best;            // strict > : earliest batch wins ties
        bb   = c ? nb : bb;
        best = c ? m : best;
        ++nb;
    }

    // monotonic float->uint, truncate low 9 bits, pack batch id
    unsigned u = __float_as_uint(best);
    unsigned s = (u & 0x80000000u) ? ~u : (u | 0x80000000u);
    part[chunk * NTOK + tok] = (s & ~IDMASK) | (unsigned)(chunk * NBATCH + bb);

    if (blockIdx.x == 0 && blockIdx.y == 0 && threadIdx.x == 0)
        *cnt = 0;   // for merge's last-block ticket (visible at dispatch boundary)
}

// Kernel B: per token umax over 16 keys -> winning batch; recompute the 16
// dots exactly and take first-max argmax; sum |x-e|; block reduce; last
// block (ticket) reduces the 128 block sums and writes the loss.
__global__ __launch_bounds__(TPB) void vq_merge(
    const float4* __restrict__ x,
    const float4* __restrict__ emb,
    const unsigned* __restrict__ part,
    float* __restrict__ blocksum,
    unsigned* __restrict__ cnt,
    float* __restrict__ out) {

    const int tok = blockIdx.x * TPB + threadIdx.x;

    unsigned key = part[tok];                    // chunk 0
    #pragma unroll
    for (int c = 1; c < NCHUNK; ++c) {           // coalesced per c
        unsigned k = part[c * NTOK + tok];
        key = (k > key) ? k : key;
    }

    const float4* eb = emb + (key & IDMASK) * BATCH;
    const float4 xv = x[tok];

    float best = -INFINITY;
    float4 e = eb[0];
    #pragma unroll
    for (int j = 0; j < BATCH; ++j) {            // ascending: first-max wins
        float4 c4 = eb[j];
        float d = fmaf(xv.w, c4.w, fmaf(xv.z, c4.z, fmaf(xv.y, c4.y, xv.x * c4.x)));
        bool c = d > best;
        best = c ? d : best;
        e.x = c ? c4.x : e.x;  e.y = c ? c4.y : e.y;
        e.z = c ? c4.z : e.z;  e.w = c ? c4.w : e.w;
    }

    float s = fabsf(xv.x - e.x) + fabsf(xv.y - e.y)
            + fabsf(xv.z - e.z) + fabsf(xv.w - e.w);

    #pragma unroll
    for (int off = 32; off > 0; off >>= 1)
        s += __shfl_down(s, off, 64);

    __shared__ float ws[TPB / 64];
    __shared__ bool  sLast;
    if ((threadIdx.x & 63) == 0) ws[threadIdx.x >> 6] = s;
    __syncthreads();

    if (threadIdx.x == 0) {
        blocksum[blockIdx.x] = ws[0] + ws[1] + ws[2] + ws[3];
        __threadfence();
        unsigned old = __hip_atomic_fetch_add(cnt, 1u, __ATOMIC_ACQ_REL,
                                              __HIP_MEMORY_SCOPE_AGENT);
        sLast = (old == NMB - 1);
    }
    __syncthreads();
    if (!sLast) return;

    float t = 0.f;
    if (threadIdx.x < NMB)
        t = ((const volatile float*)blocksum)[threadIdx.x];
    #pragma unroll
    for (int off = 32; off > 0; off >>= 1)
        t += __shfl_down(t, off, 64);
    if ((threadIdx.x & 63) == 0) ws[threadIdx.x >> 6] = t;
    __syncthreads();
    if (threadIdx.x == 0)
        out[0] = (ws[0] + ws[1]) * (2.0f / (float)(NTOK * DIM));
}

extern "C" void kernel_launch(void* const* d_in, const int* in_sizes, int n_in,
                              void* d_out, int out_size, void* d_ws, size_t ws_size,
                              hipStream_t stream) {
    const float4* x4  = (const float4*)d_in[0];   // [8,4096,4] fp32
    const float*  emb = (const float*)d_in[1];    // [8192,4]   fp32
    float* out = (float*)d_out;

    // ws: part keys (2 MB) | blocksum (512 B) | cnt (4 B)
    char* w = (char*)d_ws;
    unsigned* part     = (unsigned*)w;
    float*    blocksum = (float*)(w + (size_t)NCHUNK * NTOK * 4);
    unsigned* cnt      = (unsigned*)(w + (size_t)NCHUNK * NTOK * 4 + NMB * 4);

    dim3 g1(NTOK / TPB, NCHUNK);
    vq_scan <<<g1,  TPB, 0, stream>>>(x4, emb, part, cnt);
    vq_merge<<<NMB, TPB, 0, stream>>>(x4, (const float4*)emb, part,
                                      blocksum, cnt, out);
}

// Round 7
// 112.999 us; speedup vs baseline: 2.7438x; 1.5167x over previous
//
#include <hip/hip_runtime.h>
#include <hip/hip_bf16.h>
#include <math.h>

#define NUM_EMB 8192
#define NTOK    32768                 // B*L = 8*4096
#define NCHUNK  4
#define CHUNK   (NUM_EMB / NCHUNK)    // 2048 embeddings per chunk
#define SB      128                   // superbatch (merge re-scan granularity)
#define NSB     (CHUNK / SB)          // 16 superbatches per chunk
#define SBMASK  63u                   // 4*16 = 64 global superbatch ids
#define TPB     256
#define NMB     (NTOK / TPB)          // 128 merge blocks

typedef __attribute__((ext_vector_type(8))) short short8;   // 8 bf16 (A/B frag)
typedef __attribute__((ext_vector_type(4))) float f32x4;    // C/D frag

// pack four bf16x2 into one 8-bf16 fragment (pure register bitcast)
__device__ __forceinline__ short8 pack2(__hip_bfloat162 a, __hip_bfloat162 b,
                                        __hip_bfloat162 c, __hip_bfloat162 d) {
    union { short8 s; __hip_bfloat162 h[4]; } u;
    u.h[0] = a; u.h[1] = b; u.h[2] = c; u.h[3] = d;
    return u.s;
}

// fp32 -> bf16 hi + bf16(residual lo); hi+lo recovers ~2^-17 relative
__device__ __forceinline__ void split4(float4 v,
        __hip_bfloat162& hxy, __hip_bfloat162& hzw,
        __hip_bfloat162& lxy, __hip_bfloat162& lzw) {
    hxy = __float22bfloat162_rn(make_float2(v.x, v.y));
    hzw = __float22bfloat162_rn(make_float2(v.z, v.w));
    float lx = v.x - __low2float(hxy);
    float ly = v.y - __high2float(hxy);
    float lz = v.z - __low2float(hzw);
    float lw = v.w - __high2float(hzw);
    lxy = __float22bfloat162_rn(make_float2(lx, ly));
    lzw = __float22bfloat162_rn(make_float2(lz, lw));
}

// Kernel A: MFMA scan. Each wave: 16 tokens x one 2048-emb chunk.
// A frag (16x16x32, A[m=lane&15][k=quad*8+j]): quads 0,2 = [xhi,xhi],
// quads 1,3 = [xlo,xlo]. B frag (B[n=lane&15][k=quad*8+j]): [ehi,elo] all
// quads. Then D = 2*(xhi+xlo)·(ehi+elo) = 2*dot, fp32-grade precision.
// Value-max per lane reg via v_max3 over MFMA pairs; superbatch id tracked
// at 128-emb granularity; quad-butterfly umax on packed sort keys.
__global__ __launch_bounds__(TPB, 4) void vq_scan(
    const float4* __restrict__ x,
    const float4* __restrict__ emb,
    unsigned* __restrict__ part,      // [NCHUNK][NTOK] packed keys
    unsigned* __restrict__ cnt) {

    if (blockIdx.x == 0 && blockIdx.y == 0 && threadIdx.x == 0)
        *cnt = 0;   // merge's ticket; visible at dispatch boundary

    const int lane  = threadIdx.x & 63;
    const int col   = lane & 15;            // n (emb) / m (token) free index
    const int quad  = lane >> 4;            // 0..3
    const int grp   = blockIdx.x * 4 + (threadIdx.x >> 6);   // 16-token group
    const int chunk = blockIdx.y;

    // ---- A fragment (fixed for the whole scan) ----
    float4 xv = x[grp * 16 + col];
    __hip_bfloat162 hxy, hzw, lxy, lzw;
    split4(xv, hxy, hzw, lxy, lzw);
    const short8 afrag = (quad & 1) ? pack2(lxy, lzw, lxy, lzw)
                                    : pack2(hxy, hzw, hxy, hzw);

    const float4* eb = emb + chunk * CHUNK + col;   // lane's emb stream

    float gbest[4] = {-INFINITY, -INFINITY, -INFINITY, -INFINITY};
    int   gsb[4]   = {0, 0, 0, 0};
    const f32x4 zero = {0.f, 0.f, 0.f, 0.f};

    for (int sb = 0; sb < NSB; ++sb) {
        float vmax[4];
        #pragma unroll
        for (int g = 0; g < SB / 32; ++g) {          // 4 groups x 2 MFMAs
            float4 e0 = eb[sb * SB + g * 32];
            float4 e1 = eb[sb * SB + g * 32 + 16];
            __hip_bfloat162 h0a, h0b, l0a, l0b, h1a, h1b, l1a, l1b;
            split4(e0, h0a, h0b, l0a, l0b);
            split4(e1, h1a, h1b, l1a, l1b);
            short8 b0 = pack2(h0a, h0b, l0a, l0b);
            short8 b1 = pack2(h1a, h1b, l1a, l1b);
            f32x4 d0 = __builtin_amdgcn_mfma_f32_16x16x32_bf16(afrag, b0, zero, 0, 0, 0);
            f32x4 d1 = __builtin_amdgcn_mfma_f32_16x16x32_bf16(afrag, b1, zero, 0, 0, 0);
            #pragma unroll
            for (int r = 0; r < 4; ++r) {
                float m2 = fmaxf(d0[r], d1[r]);      // v_max3 with next line
                vmax[r] = (g == 0) ? m2 : fmaxf(vmax[r], m2);
            }
        }
        #pragma unroll
        for (int r = 0; r < 4; ++r) {                // ascending sb: first-max
            bool c = vmax[r] > gbest[r];
            gbest[r] = c ? vmax[r] : gbest[r];
            gsb[r]   = c ? sb : gsb[r];
        }
    }

    // ---- pack sort key, butterfly-umax across the 16 lanes of each quad ----
    const int sbbase = chunk * NSB;
    #pragma unroll
    for (int r = 0; r < 4; ++r) {
        unsigned u = __float_as_uint(gbest[r]);
        unsigned s = u ^ ((unsigned)((int)u >> 31) | 0x80000000u);  // sortable
        unsigned k = (s & ~SBMASK) | (63u - (unsigned)(sbbase + gsb[r]));
        #pragma unroll
        for (int m = 8; m >= 1; m >>= 1) {           // within-quad butterfly
            unsigned o = (unsigned)__shfl_xor((int)k, m, 64);
            k = (o > k) ? o : k;
        }
        if (col == r)                                 // one lane per quad
            part[chunk * NTOK + grp * 16 + quad * 4 + r] = k;   // row = quad*4+r
    }
}

// Kernel B: per token umax over 4 chunk keys -> winning superbatch; exact
// fp32 first-max re-scan of its 128 embeddings; |x-e| sum; block reduce;
// last-block ticket reduces 128 block sums and writes the loss.
__global__ __launch_bounds__(TPB) void vq_merge(
    const float4* __restrict__ x,
    const float4* __restrict__ emb,
    const unsigned* __restrict__ part,
    float* __restrict__ blocksum,
    unsigned* __restrict__ cnt,
    float* __restrict__ out) {

    const int tok = blockIdx.x * TPB + threadIdx.x;

    unsigned key = part[tok];
    #pragma unroll
    for (int c = 1; c < NCHUNK; ++c) {
        unsigned k = part[c * NTOK + tok];
        key = (k > key) ? k : key;
    }
    const int sbid = 63 - (int)(key & SBMASK);
    const float4* ebase = emb + sbid * SB;
    const float4 xv = x[tok];

    float best = -INFINITY;
    float4 e = xv;                                   // overwritten at j=0
    #pragma unroll 4
    for (int j = 0; j < SB; ++j) {                   // ascending: first-max
        float4 c4 = ebase[j];
        float d = fmaf(xv.w, c4.w, fmaf(xv.z, c4.z, fmaf(xv.y, c4.y, xv.x * c4.x)));
        bool c = d > best;
        best = c ? d : best;
        e.x = c ? c4.x : e.x;  e.y = c ? c4.y : e.y;
        e.z = c ? c4.z : e.z;  e.w = c ? c4.w : e.w;
    }

    float s = fabsf(xv.x - e.x) + fabsf(xv.y - e.y)
            + fabsf(xv.z - e.z) + fabsf(xv.w - e.w);

    #pragma unroll
    for (int off = 32; off > 0; off >>= 1)
        s += __shfl_down(s, off, 64);

    __shared__ float ws2[TPB / 64];
    __shared__ bool  sLast;
    if ((threadIdx.x & 63) == 0) ws2[threadIdx.x >> 6] = s;
    __syncthreads();

    if (threadIdx.x == 0) {
        blocksum[blockIdx.x] = ws2[0] + ws2[1] + ws2[2] + ws2[3];
        __threadfence();
        unsigned old = __hip_atomic_fetch_add(cnt, 1u, __ATOMIC_ACQ_REL,
                                              __HIP_MEMORY_SCOPE_AGENT);
        sLast = (old == NMB - 1);
    }
    __syncthreads();
    if (!sLast) return;

    float t = 0.f;
    if (threadIdx.x < NMB)
        t = ((const volatile float*)blocksum)[threadIdx.x];
    #pragma unroll
    for (int off = 32; off > 0; off >>= 1)
        t += __shfl_down(t, off, 64);
    if ((threadIdx.x & 63) == 0) ws2[threadIdx.x >> 6] = t;
    __syncthreads();
    if (threadIdx.x == 0)
        out[0] = (ws2[0] + ws2[1]) * (2.0f / (float)(NTOK * 4));
}

extern "C" void kernel_launch(void* const* d_in, const int* in_sizes, int n_in,
                              void* d_out, int out_size, void* d_ws, size_t ws_size,
                              hipStream_t stream) {
    const float4* x4  = (const float4*)d_in[0];   // [8,4096,4] fp32
    const float4* emb = (const float4*)d_in[1];   // [8192,4]   fp32
    float* out = (float*)d_out;

    // ws: part keys (512 KB) | blocksum (512 B) | cnt (4 B)
    char* w = (char*)d_ws;
    unsigned* part     = (unsigned*)w;
    float*    blocksum = (float*)(w + (size_t)NCHUNK * NTOK * 4);
    unsigned* cnt      = (unsigned*)(w + (size_t)NCHUNK * NTOK * 4 + NMB * 4);

    // scan: 2048 token-groups x 4 chunks; 256 thr = 4 waves = 4 groups/block
    dim3 g1(NTOK / 64, NCHUNK);      // (512, 4)
    vq_scan <<<g1,  TPB, 0, stream>>>(x4, emb, part, cnt);
    vq_merge<<<NMB, TPB, 0, stream>>>(x4, emb, part, blocksum, cnt, out);
}

// Round 8
// 80.449 us; speedup vs baseline: 3.8539x; 1.4046x over previous
//
#include <hip/hip_runtime.h>
#include <hip/hip_bf16.h>
#include <math.h>

#define NUM_EMB 8192
#define NTOK    32768                 // B*L = 8*4096
#define NCHUNK  8
#define CHUNK   (NUM_EMB / NCHUNK)    // 1024 embeddings per chunk
#define SB      32                    // superbatch = 1 MFMA = 32 embeddings
#define NSB     (CHUNK / SB)          // 32 sbs per chunk; 256 global ids
#define SBMASK  255u
#define TPB     256
#define NMB     (NTOK / TPB)          // 128 merge blocks

typedef __attribute__((ext_vector_type(8)))  short short8;   // 8 bf16
typedef __attribute__((ext_vector_type(16))) float f32x16;   // 32x32 C/D frag

__device__ __forceinline__ short8 pack2(__hip_bfloat162 a, __hip_bfloat162 b,
                                        __hip_bfloat162 c, __hip_bfloat162 d) {
    union { short8 s; __hip_bfloat162 h[4]; } u;
    u.h[0] = a; u.h[1] = b; u.h[2] = c; u.h[3] = d;
    return u.s;
}

// fp32 -> bf16 hi + bf16 residual lo (hi+lo ~ 2^-17 rel)
__device__ __forceinline__ void split4(float4 v,
        __hip_bfloat162& hxy, __hip_bfloat162& hzw,
        __hip_bfloat162& lxy, __hip_bfloat162& lzw) {
    hxy = __float22bfloat162_rn(make_float2(v.x, v.y));
    hzw = __float22bfloat162_rn(make_float2(v.z, v.w));
    lxy = __float22bfloat162_rn(make_float2(v.x - __low2float(hxy),
                                            v.y - __high2float(hxy)));
    lzw = __float22bfloat162_rn(make_float2(v.z - __low2float(hzw),
                                            v.w - __high2float(hzw)));
}

// Kernel A: 32x32x16 MFMA scan, embeddings in A, tokens in B.
// grid = (128, 8) = 1024 blocks (4/CU, 16 waves/CU). Block: stage+convert its
// 1024-emb chunk into LDS frags [ehi4|elo4] (one-time), then 4 waves x 64
// tokens scan 32 sbs: 1 ds_read_b128 -> 2 MFMAs (B-frag pair in regs).
// D (m74/m101): lane = token col (lane&31), 16 regs = 16 emb rows -> in-lane
// max tree; sb-granular id; cross-half shfl_xor(32) umax on packed key.
__global__ __launch_bounds__(TPB, 4) void vq_scan(
    const float4* __restrict__ x,
    const float4* __restrict__ emb,
    unsigned* __restrict__ part,      // [NCHUNK][NTOK] packed keys
    unsigned* __restrict__ cnt) {

    if (blockIdx.x == 0 && blockIdx.y == 0 && threadIdx.x == 0)
        *cnt = 0;   // merge's ticket; visible at the dispatch boundary

    __shared__ short8 sfrag[CHUNK];   // 16 KB
    const int chunk = blockIdx.y;

    // ---- one-time: convert chunk to hi/lo fragment layout in LDS ----
    #pragma unroll
    for (int r = 0; r < CHUNK / TPB; ++r) {
        const int i = r * TPB + threadIdx.x;
        float4 e = emb[chunk * CHUNK + i];
        __hip_bfloat162 hxy, hzw, lxy, lzw;
        split4(e, hxy, hzw, lxy, lzw);
        sfrag[i] = pack2(hxy, hzw, lxy, lzw);   // k0-3=ehi, k4-7=elo
    }
    __syncthreads();

    const int lane = threadIdx.x & 63;
    const int col  = lane & 31;
    const int half = lane >> 5;               // k-half
    const int wave = threadIdx.x >> 6;
    // wave handles two 32-token groups
    const int g0 = (blockIdx.x * 8 + wave * 2) * 32;
    const int g1 = g0 + 32;

    // ---- B fragments (tokens), fixed for the whole scan ----
    // B[n=col][k]: half0 k0-7 = [xhi,xhi], half1 k8-15 = [xlo,xlo]
    __hip_bfloat162 hxy, hzw, lxy, lzw;
    float4 xv0 = x[g0 + col];
    split4(xv0, hxy, hzw, lxy, lzw);
    const short8 bf0 = half ? pack2(lxy, lzw, lxy, lzw)
                            : pack2(hxy, hzw, hxy, hzw);
    float4 xv1 = x[g1 + col];
    split4(xv1, hxy, hzw, lxy, lzw);
    const short8 bf1 = half ? pack2(lxy, lzw, lxy, lzw)
                            : pack2(hxy, hzw, hxy, hzw);

    const f32x16 zero = {0,0,0,0,0,0,0,0,0,0,0,0,0,0,0,0};
    float best0 = -INFINITY, best1 = -INFINITY;
    int   bsb0 = 0, bsb1 = 0;

    #pragma unroll 8
    for (int sb = 0; sb < NSB; ++sb) {
        // A frag: emb row = col, same 16B for both halves (k-layout [ehi,elo])
        short8 af = sfrag[sb * SB + col];
        f32x16 d0 = __builtin_amdgcn_mfma_f32_32x32x16_bf16(af, bf0, zero, 0, 0, 0);
        f32x16 d1 = __builtin_amdgcn_mfma_f32_32x32x16_bf16(af, bf1, zero, 0, 0, 0);
        float m0 = fmaxf(fmaxf(fmaxf(fmaxf(d0[0], d0[1]),  fmaxf(d0[2], d0[3])),
                               fmaxf(fmaxf(d0[4], d0[5]),  fmaxf(d0[6], d0[7]))),
                         fmaxf(fmaxf(fmaxf(d0[8], d0[9]),  fmaxf(d0[10], d0[11])),
                               fmaxf(fmaxf(d0[12], d0[13]), fmaxf(d0[14], d0[15]))));
        float m1 = fmaxf(fmaxf(fmaxf(fmaxf(d1[0], d1[1]),  fmaxf(d1[2], d1[3])),
                               fmaxf(fmaxf(d1[4], d1[5]),  fmaxf(d1[6], d1[7]))),
                         fmaxf(fmaxf(fmaxf(d1[8], d1[9]),  fmaxf(d1[10], d1[11])),
                               fmaxf(fmaxf(d1[12], d1[13]), fmaxf(d1[14], d1[15]))));
        bool c0 = m0 > best0;   // ascending sb, strict > : earliest sb wins
        bool c1 = m1 > best1;
        bsb0  = c0 ? sb : bsb0;   best0 = c0 ? m0 : best0;
        bsb1  = c1 ? sb : bsb1;   best1 = c1 ? m1 : best1;
    }

    // ---- pack sortable keys, combine the two k-halves, store ----
    const int sbbase = chunk * NSB;
    unsigned u0 = __float_as_uint(best0);
    unsigned s0 = ((int)u0 < 0) ? ~u0 : (u0 | 0x80000000u);
    unsigned k0 = (s0 & ~SBMASK) | (255u - (unsigned)(sbbase + bsb0));
    unsigned u1 = __float_as_uint(best1);
    unsigned s1 = ((int)u1 < 0) ? ~u1 : (u1 | 0x80000000u);
    unsigned k1 = (s1 & ~SBMASK) | (255u - (unsigned)(sbbase + bsb1));

    unsigned o0 = (unsigned)__shfl_xor((int)k0, 32, 64);
    k0 = (o0 > k0) ? o0 : k0;
    unsigned o1 = (unsigned)__shfl_xor((int)k1, 32, 64);
    k1 = (o1 > k1) ? o1 : k1;

    if (half == 0) {
        part[chunk * NTOK + g0 + col] = k0;
        part[chunk * NTOK + g1 + col] = k1;
    }
}

// Kernel B: per token umax over 8 chunk keys -> winning 32-emb sb; exact
// fp32 first-max re-scan; |x-e| sum; block reduce; last-block ticket final.
__global__ __launch_bounds__(TPB) void vq_merge(
    const float4* __restrict__ x,
    const float4* __restrict__ emb,
    const unsigned* __restrict__ part,
    float* __restrict__ blocksum,
    unsigned* __restrict__ cnt,
    float* __restrict__ out) {

    const int tok = blockIdx.x * TPB + threadIdx.x;

    unsigned key = part[tok];
    #pragma unroll
    for (int c = 1; c < NCHUNK; ++c) {
        unsigned k = part[c * NTOK + tok];
        key = (k > key) ? k : key;
    }
    const int sbid = 255 - (int)(key & SBMASK);
    const float4* eb = emb + sbid * SB;
    const float4 xv = x[tok];

    float best = -INFINITY;
    float4 e = xv;                                   // overwritten at j=0
    #pragma unroll 4
    for (int j = 0; j < SB; ++j) {                   // ascending: first-max
        float4 c4 = eb[j];
        float d = fmaf(xv.w, c4.w, fmaf(xv.z, c4.z, fmaf(xv.y, c4.y, xv.x * c4.x)));
        bool c = d > best;
        best = c ? d : best;
        e.x = c ? c4.x : e.x;  e.y = c ? c4.y : e.y;
        e.z = c ? c4.z : e.z;  e.w = c ? c4.w : e.w;
    }

    float s = fabsf(xv.x - e.x) + fabsf(xv.y - e.y)
            + fabsf(xv.z - e.z) + fabsf(xv.w - e.w);

    #pragma unroll
    for (int off = 32; off > 0; off >>= 1)
        s += __shfl_down(s, off, 64);

    __shared__ float ws2[TPB / 64];
    __shared__ bool  sLast;
    if ((threadIdx.x & 63) == 0) ws2[threadIdx.x >> 6] = s;
    __syncthreads();

    if (threadIdx.x == 0) {
        blocksum[blockIdx.x] = ws2[0] + ws2[1] + ws2[2] + ws2[3];
        __threadfence();
        unsigned old = __hip_atomic_fetch_add(cnt, 1u, __ATOMIC_ACQ_REL,
                                              __HIP_MEMORY_SCOPE_AGENT);
        sLast = (old == NMB - 1);
    }
    __syncthreads();
    if (!sLast) return;

    float t = 0.f;
    if (threadIdx.x < NMB)
        t = ((const volatile float*)blocksum)[threadIdx.x];
    #pragma unroll
    for (int off = 32; off > 0; off >>= 1)
        t += __shfl_down(t, off, 64);
    if ((threadIdx.x & 63) == 0) ws2[threadIdx.x >> 6] = t;
    __syncthreads();
    if (threadIdx.x == 0)
        out[0] = (ws2[0] + ws2[1]) * (2.0f / (float)(NTOK * 4));
}

extern "C" void kernel_launch(void* const* d_in, const int* in_sizes, int n_in,
                              void* d_out, int out_size, void* d_ws, size_t ws_size,
                              hipStream_t stream) {
    const float4* x4  = (const float4*)d_in[0];   // [8,4096,4] fp32
    const float4* emb = (const float4*)d_in[1];   // [8192,4]   fp32
    float* out = (float*)d_out;

    // ws: part keys (1 MB) | blocksum (512 B) | cnt (4 B)
    char* w = (char*)d_ws;
    unsigned* part     = (unsigned*)w;
    float*    blocksum = (float*)(w + (size_t)NCHUNK * NTOK * 4);
    unsigned* cnt      = (unsigned*)(w + (size_t)NCHUNK * NTOK * 4 + NMB * 4);

    dim3 g1(128, NCHUNK);            // 128 token-blocks (256 tok) x 8 chunks
    vq_scan <<<g1,  TPB, 0, stream>>>(x4, emb, part, cnt);
    vq_merge<<<NMB, TPB, 0, stream>>>(x4, emb, part, blocksum, cnt, out);
}